// Round 1
// baseline (587.453 us; speedup 1.0000x reference)
//
#include <hip/hip_runtime.h>

// GCN: out = relu(Ahat @ (X W1) + b1) -> relu(Ahat @ (. W2) + b2) -> @ Wfc + bfc
// Ahat = D^-1/2 (A+I) D^-1/2.
// Identity used: layer(v) = dis[v] * ( sum_{e: dst=v} hs[src_e] + hs[v] ),
// where hs[i] = (x[i] @ W) * dis[i].  Self-loops handled analytically.

constexpr int F = 16;

__global__ void init_kernel(float* __restrict__ deg, float* __restrict__ acc, int N) {
    int i = blockIdx.x * blockDim.x + threadIdx.x;
    if (i < N * F) acc[i] = 0.0f;
    if (i < N) deg[i] = 1.0f;   // self-loop contributes 1 to every node's degree
}

__global__ void deg_kernel(const int* __restrict__ dst, float* __restrict__ deg, int E) {
    int e = blockIdx.x * blockDim.x + threadIdx.x;
    if (e < E) unsafeAtomicAdd(&deg[dst[e]], 1.0f);
}

// hs[i][j] = (sum_k x[i][k] * W[k][j]) * rsqrt(deg[i]) ; 16 nodes per 256-thread block
__global__ void mv_scale_kernel(const float* __restrict__ x, const float* __restrict__ W,
                                const float* __restrict__ deg, float* __restrict__ hs, int N) {
    __shared__ float xs[16][17];
    __shared__ float ws[16][16];
    int tid = threadIdx.x;
    int n = tid >> 4, j = tid & 15;
    int node = blockIdx.x * 16 + n;
    ws[n][j] = W[tid];                       // W[k=n][j]
    xs[n][j] = (node < N) ? x[node * F + j] : 0.0f;
    __syncthreads();
    float acc = 0.f;
#pragma unroll
    for (int k = 0; k < 16; ++k) acc += xs[n][k] * ws[k][j];
    if (node < N) hs[node * F + j] = acc * rsqrtf(deg[node]);
}

// acc[dst][j] += hs[src][j]  — one thread per (edge, feature)
__global__ void scatter_kernel(const int* __restrict__ src, const int* __restrict__ dst,
                               const float* __restrict__ hs, float* __restrict__ acc, int E) {
    int gid = blockIdx.x * blockDim.x + threadIdx.x;
    int e = gid >> 4;
    if (e < E) {
        int j = gid & 15;
        int s = src[e], d = dst[e];
        unsafeAtomicAdd(&acc[d * F + j], hs[s * F + j]);
    }
}

// h1 = relu(dis*(acc + hs1) + b1); hs2 = (h1 @ W2) * dis ; re-zeros acc for layer 2
__global__ void ep1_mv2_kernel(const float* __restrict__ hs1, float* __restrict__ acc,
                               const float* __restrict__ W2, const float* __restrict__ b1,
                               const float* __restrict__ deg, float* __restrict__ hs2, int N) {
    __shared__ float hsld[16][17];
    __shared__ float ws[16][16];
    int tid = threadIdx.x;
    int n = tid >> 4, j = tid & 15;
    int node = blockIdx.x * 16 + n;
    ws[n][j] = W2[tid];
    float dis = 0.f, h1 = 0.f;
    if (node < N) {
        dis = rsqrtf(deg[node]);
        int idx = node * F + j;
        float v = dis * (acc[idx] + hs1[idx]) + b1[j];
        h1 = fmaxf(v, 0.f);
        acc[idx] = 0.0f;                     // re-zero for second scatter
    }
    hsld[n][j] = h1;
    __syncthreads();
    float s = 0.f;
#pragma unroll
    for (int k = 0; k < 16; ++k) s += hsld[n][k] * ws[k][j];
    if (node < N) hs2[node * F + j] = s * dis;
}

// out[i] = sum_j relu(dis*(acc + hs2) + b2)[j] * Wfc[j] + bfc
__global__ void ep2_fc_kernel(const float* __restrict__ hs2, const float* __restrict__ acc,
                              const float* __restrict__ b2, const float* __restrict__ Wfc,
                              const float* __restrict__ bfc, const float* __restrict__ deg,
                              float* __restrict__ out, int N) {
    int i = blockIdx.x * blockDim.x + threadIdx.x;
    if (i >= N) return;
    float dis = rsqrtf(deg[i]);
    float s = 0.f;
#pragma unroll
    for (int j = 0; j < F; ++j) {
        float v = dis * (acc[i * F + j] + hs2[i * F + j]) + b2[j];
        s += fmaxf(v, 0.f) * Wfc[j];
    }
    out[i] = s + bfc[0];
}

extern "C" void kernel_launch(void* const* d_in, const int* in_sizes, int n_in,
                              void* d_out, int out_size, void* d_ws, size_t ws_size,
                              hipStream_t stream) {
    const float* x   = (const float*)d_in[0];
    const int*   ei  = (const int*)d_in[1];
    const float* W1  = (const float*)d_in[2];
    const float* b1  = (const float*)d_in[3];
    const float* W2  = (const float*)d_in[4];
    const float* b2  = (const float*)d_in[5];
    const float* Wfc = (const float*)d_in[6];
    const float* bfc = (const float*)d_in[7];
    float* out = (float*)d_out;

    const int N = in_sizes[0] / F;        // 100000
    const int E = in_sizes[1] / 2;        // 3200000
    const int* src = ei;                  // edge_index[0]
    const int* dst = ei + E;              // edge_index[1]

    float* deg = (float*)d_ws;            // [N]
    float* hs1 = deg + N;                 // [N*F]
    float* acc = hs1 + (size_t)N * F;     // [N*F]
    float* hs2 = acc + (size_t)N * F;     // [N*F]

    const int T = 256;
    init_kernel<<<(N * F + T - 1) / T, T, 0, stream>>>(deg, acc, N);
    deg_kernel<<<(E + T - 1) / T, T, 0, stream>>>(dst, deg, E);
    mv_scale_kernel<<<(N + 15) / 16, T, 0, stream>>>(x, W1, deg, hs1, N);
    const long tot = (long)E * F;
    scatter_kernel<<<(int)((tot + T - 1) / T), T, 0, stream>>>(src, dst, hs1, acc, E);
    ep1_mv2_kernel<<<(N + 15) / 16, T, 0, stream>>>(hs1, acc, W2, b1, deg, hs2, N);
    scatter_kernel<<<(int)((tot + T - 1) / T), T, 0, stream>>>(src, dst, hs2, acc, E);
    ep2_fc_kernel<<<(N + T - 1) / T, T, 0, stream>>>(hs2, acc, b2, Wfc, bfc, deg, out, N);
}